// Round 11
// baseline (187.859 us; speedup 1.0000x reference)
//
#include <hip/hip_runtime.h>

// ---------------------------------------------------------------------------
// MultiHeadSelfAttention: x[2,2048,1024] fp32 -> out[2,2048,1024] fp32
//   qkv = x @ qkv_w^T + qkv_b ; reverse-causal attn (key >= query) ; proj.
// bf16 MFMA everywhere (tol 2.39e-2 >> bf16 err), fp32 accum.
// Split-K attention (valid because softmax uses static reference M=0:
// partials are linear) with combine fused into the out-proj A-staging.
// ---------------------------------------------------------------------------

#define D_MODEL 1024
#define NHEAD 16
#define HEAD_DIM 64
#define INNER 1024
#define BATCH 2
#define T_SEQ 2048
#define TOKENS (BATCH * T_SEQ)

typedef float f32x4 __attribute__((ext_vector_type(4)));
typedef __bf16 bf16x8 __attribute__((ext_vector_type(8)));
typedef __bf16 bf16x4 __attribute__((ext_vector_type(4)));
typedef unsigned short u16x8 __attribute__((ext_vector_type(8)));
typedef unsigned int u32x2 __attribute__((ext_vector_type(2)));
typedef short s16x4 __attribute__((ext_vector_type(4)));

__device__ __forceinline__ unsigned short f2bf(float f) {
    unsigned int u = __builtin_bit_cast(unsigned int, f);
    u = (u + 0x7FFFu + ((u >> 16) & 1u)) >> 16;   // round-to-nearest-even
    return (unsigned short)u;
}
__device__ __forceinline__ float bf2f(unsigned short u) {
    return __builtin_bit_cast(float, (unsigned int)u << 16);
}

__device__ __forceinline__ unsigned int cvt_pk_bf16(float lo, float hi) {
    unsigned int r;
    asm("v_cvt_pk_bf16_f32 %0, %1, %2" : "=v"(r) : "v"(lo), "v"(hi));
    return r;
}

__device__ __forceinline__ void gload_lds16(const void* g, void* l) {
    __builtin_amdgcn_global_load_lds(
        (const __attribute__((address_space(1))) unsigned int*)g,
        (__attribute__((address_space(3))) unsigned int*)l, 16, 0, 0);
}

__device__ __forceinline__ unsigned ldsa(const void* p) {
    return (unsigned)(unsigned long long)(const __attribute__((address_space(3))) void*)p;
}

// Fused wait+barrier: ONE volatile asm w/ memory clobber, vmcnt NOT drained.
__device__ __forceinline__ void lds_barrier() {
    asm volatile("s_waitcnt lgkmcnt(0)\n\ts_barrier" ::: "memory");
}

#define TR1(dst, addr, ofs)                                                  \
    asm volatile("ds_read_b64_tr_b16 %0, %1 offset:" #ofs                    \
                 : "=&v"(dst) : "v"(addr))

__device__ __forceinline__ f32x4 mfma16(u32x2 a, u32x2 b, f32x4 c) {
#if __has_builtin(__builtin_amdgcn_mfma_f32_16x16x16_bf16)
    return __builtin_amdgcn_mfma_f32_16x16x16_bf16(
        __builtin_bit_cast(bf16x4, a), __builtin_bit_cast(bf16x4, b), c, 0, 0, 0);
#elif __has_builtin(__builtin_amdgcn_mfma_f32_16x16x16bf16_1k)
    return __builtin_amdgcn_mfma_f32_16x16x16bf16_1k(
        __builtin_bit_cast(s16x4, a), __builtin_bit_cast(s16x4, b), c, 0, 0, 0);
#else
    f32x4 d = c;
    asm volatile("s_nop 1\n\tv_mfma_f32_16x16x16_bf16 %0, %1, %2, %0"
                 : "+v"(d) : "v"(a), "v"(b));
    return d;
#endif
}

// ---------------------------------------------------------------------------
__global__ __launch_bounds__(256) void cvt_f32_bf16(
    const float* __restrict__ in, unsigned short* __restrict__ out, int n) {
    int i = (blockIdx.x * 256 + threadIdx.x) * 4;
    if (i < n) {
        float4 v = *reinterpret_cast<const float4*>(in + i);
        ushort4 o;
        o.x = f2bf(v.x); o.y = f2bf(v.y); o.z = f2bf(v.z); o.w = f2bf(v.w);
        *reinterpret_cast<ushort4*>(out + i) = o;
    }
}

// ---------------------------------------------------------------------------
// NT GEMM 128x128, BK=64 (R10-proven) -- QKV only now.
// ---------------------------------------------------------------------------
__global__ __launch_bounds__(256) void gemm_nt(
    const unsigned short* __restrict__ A,   // [M][K] bf16
    const unsigned short* __restrict__ Bw,  // [N][K] bf16
    const float* __restrict__ bias,         // [N]
    unsigned short* __restrict__ Cp, int M, int N, int K,
    int qcols, float qscale) {
    constexpr int BK = 64;
    __shared__ __align__(16) unsigned short Al[128 * BK];
    __shared__ __align__(16) unsigned short Bl[128 * BK];
    const int tid = threadIdx.x;
    const int wid = tid >> 6, lane = tid & 63, lr = lane & 15, lg = lane >> 4;
    const int m0 = blockIdx.y * 128, n0 = blockIdx.x * 128;
    const int wr = wid >> 1, wc = wid & 1;

    f32x4 acc[4][4] = {};

    int arow[4], acol[4];
#pragma unroll
    for (int c = 0; c < 4; c++) {
        const int byte = tid * 16 + c * 4096;
        const int row = byte >> 7;
        const int ls = ((byte >> 4) & 7) ^ (row & 7);
        arow[c] = row;
        acol[c] = ls * 8;
    }

    for (int k0 = 0; k0 < K; k0 += BK) {
#pragma unroll
        for (int c = 0; c < 4; c++)
            gload_lds16(A + (m0 + arow[c]) * K + k0 + acol[c],
                        (char*)Al + wid * 1024 + c * 4096);
#pragma unroll
        for (int c = 0; c < 4; c++)
            gload_lds16(Bw + (n0 + arow[c]) * K + k0 + acol[c],
                        (char*)Bl + wid * 1024 + c * 4096);
        __syncthreads();

        bf16x8 af[4][2], bfr[4][2];
#pragma unroll
        for (int m = 0; m < 4; m++)
#pragma unroll
            for (int hk = 0; hk < 2; hk++) {
                const int row = wr * 64 + m * 16 + lr;
                const int ps = (hk * 4 + lg) ^ (lr & 7);
                af[m][hk] = *(const bf16x8*)((char*)Al + row * 128 + ps * 16);
            }
#pragma unroll
        for (int n = 0; n < 4; n++)
#pragma unroll
            for (int hk = 0; hk < 2; hk++) {
                const int row = wc * 64 + n * 16 + lr;
                const int ps = (hk * 4 + lg) ^ (lr & 7);
                bfr[n][hk] = *(const bf16x8*)((char*)Bl + row * 128 + ps * 16);
            }
#pragma unroll
        for (int m = 0; m < 4; m++)
#pragma unroll
            for (int n = 0; n < 4; n++) {
                acc[m][n] = __builtin_amdgcn_mfma_f32_16x16x32_bf16(
                    af[m][0], bfr[n][0], acc[m][n], 0, 0, 0);
                acc[m][n] = __builtin_amdgcn_mfma_f32_16x16x32_bf16(
                    af[m][1], bfr[n][1], acc[m][n], 0, 0, 0);
            }
        __syncthreads();
    }

#pragma unroll
    for (int n = 0; n < 4; n++) {
        const int col = n0 + wc * 64 + n * 16 + lr;
        const float bv = bias[col];
        const float sc = (col < qcols) ? qscale : 1.0f;
#pragma unroll
        for (int m = 0; m < 4; m++) {
            const int row = m0 + wr * 64 + m * 16 + lg * 4;
#pragma unroll
            for (int i = 0; i < 4; i++)
                Cp[(long)(row + i) * N + col] = f2bf((acc[m][n][i] + bv) * sc);
        }
    }
}

// ---------------------------------------------------------------------------
// Out-projection GEMM 64x128, BK=64, with fused split-K attention combine:
// A[m][k] = (p0[m][k] + p1[m][k]) / (ls0[m][head] + ls1[m][head]),
// reg-staged into the same swizzled LDS layout gload would produce.
// ---------------------------------------------------------------------------
__global__ __launch_bounds__(256) void gemm_out(
    const unsigned short* __restrict__ p0,   // [M][1024] bf16 partial accO
    const unsigned short* __restrict__ p1,
    const float* __restrict__ ls0,           // [M][16] fp32 partial lsum
    const float* __restrict__ ls1,
    const unsigned short* __restrict__ Bw,   // [N][K] bf16 (out_w)
    const float* __restrict__ bias,          // [N]
    float* __restrict__ Cp, int M, int N, int K) {
    constexpr int BK = 64;
    __shared__ __align__(16) unsigned short Al[64 * BK];
    __shared__ __align__(16) unsigned short Bl[128 * BK];
    const int tid = threadIdx.x;
    const int wid = tid >> 6, lane = tid & 63, lr = lane & 15, lg = lane >> 4;
    const int m0 = blockIdx.y * 64, n0 = blockIdx.x * 128;

    f32x4 acc[4][2] = {};

    int arow[4], acol[4];
#pragma unroll
    for (int c = 0; c < 4; c++) {
        const int byte = tid * 16 + c * 4096;
        const int row = byte >> 7;
        const int ls = ((byte >> 4) & 7) ^ (row & 7);
        arow[c] = row;
        acol[c] = ls * 8;
    }

    for (int k0 = 0; k0 < K; k0 += BK) {
        const int head = k0 >> 6;  // acol < 64 -> head uniform per k-step
        // ---- A: reg-staged combine (c = 0,1 cover 64 rows) ----
#pragma unroll
        for (int c = 0; c < 2; c++) {
            const int row = m0 + arow[c];
            const int gcol = k0 + acol[c];
            u16x8 a0 = *(const u16x8*)(p0 + (size_t)row * INNER + gcol);
            u16x8 a1 = *(const u16x8*)(p1 + (size_t)row * INNER + gcol);
            const float l = ls0[row * 16 + head] + ls1[row * 16 + head];
            const float r = __builtin_amdgcn_rcpf(l);
            u16x8 o;
#pragma unroll
            for (int j = 0; j < 8; j++)
                o[j] = f2bf((bf2f(a0[j]) + bf2f(a1[j])) * r);
            *(u16x8*)((char*)Al + tid * 16 + c * 4096) = o;
        }
        // ---- B: async gload (4 chunks cover 128 rows) ----
#pragma unroll
        for (int c = 0; c < 4; c++)
            gload_lds16(Bw + (n0 + arow[c]) * K + k0 + acol[c],
                        (char*)Bl + wid * 1024 + c * 4096);
        __syncthreads();  // drains vmcnt (B) + lgkm (A writes)

        bf16x8 af[4][2], bfr[2][2];
#pragma unroll
        for (int m = 0; m < 4; m++)
#pragma unroll
            for (int hk = 0; hk < 2; hk++) {
                const int row = m * 16 + lr;
                const int ps = (hk * 4 + lg) ^ (lr & 7);
                af[m][hk] = *(const bf16x8*)((char*)Al + row * 128 + ps * 16);
            }
#pragma unroll
        for (int n = 0; n < 2; n++)
#pragma unroll
            for (int hk = 0; hk < 2; hk++) {
                const int row = wid * 32 + n * 16 + lr;
                const int ps = (hk * 4 + lg) ^ (lr & 7);
                bfr[n][hk] = *(const bf16x8*)((char*)Bl + row * 128 + ps * 16);
            }
#pragma unroll
        for (int m = 0; m < 4; m++)
#pragma unroll
            for (int n = 0; n < 2; n++) {
                acc[m][n] = __builtin_amdgcn_mfma_f32_16x16x32_bf16(
                    af[m][0], bfr[n][0], acc[m][n], 0, 0, 0);
                acc[m][n] = __builtin_amdgcn_mfma_f32_16x16x32_bf16(
                    af[m][1], bfr[n][1], acc[m][n], 0, 0, 0);
            }
        __syncthreads();
    }

#pragma unroll
    for (int n = 0; n < 2; n++) {
        const int col = n0 + wid * 32 + n * 16 + lr;
        const float bv = bias[col];
#pragma unroll
        for (int m = 0; m < 4; m++) {
            const int row = m0 + m * 16 + lg * 4;
#pragma unroll
            for (int i = 0; i < 4; i++)
                Cp[(long)(row + i) * N + col] = acc[m][n][i] + bv;
        }
    }
}

// ---------------------------------------------------------------------------
// Flash attention, reverse-causal, SPLIT-K x2 (R9 internals unchanged).
// Block (pq, s): for each half q-tile {pq, 31-pq}, s=0 takes the first
// ceil(len/2) k-tiles, s=1 the rest -> 17/16 tiles per block, uniform.
// Writes UNNORMALIZED accO (bf16) + lsum (fp32) to part s.
// ---------------------------------------------------------------------------
__global__ __launch_bounds__(256) void attn_fwd(
    const unsigned short* __restrict__ qkv,  // [TOKENS][3*INNER] bf16
    unsigned short* __restrict__ part0, unsigned short* __restrict__ part1,
    float* __restrict__ lsp0, float* __restrict__ lsp1)
{
    constexpr int KB = 64;
    __shared__ __align__(16) unsigned short Kl[2][KB * 64];   // 8 KB x2
    __shared__ __align__(16) unsigned short Vs[2][KB * 64];   // 8 KB x2

    const int tid = threadIdx.x;
    const int wid = tid >> 6, lane = tid & 63, lr = lane & 15, lg = lane >> 4;

    // XCD-pinned swizzle (1024 blocks): XCD x gets groups {x,x+8,x+16,x+24}
    const int phys = blockIdx.x;             // 0..1023
    const int xcd = phys & 7;
    const int slot = phys >> 3;              // 0..127
    const int grp = xcd + 8 * (slot >> 5);   // 0..31
    const int sub = slot & 31;
    const int pq = sub >> 1;                 // 0..15
    const int s = sub & 1;                   // split half
    const int b = grp >> 4, h = grp & 15;

    const int qA = pq * 64, qB = (31 - pq) * 64;
    unsigned short* prt = s ? part1 : part0;
    float* lsp = s ? lsp1 : lsp0;

    int kwo[2], roffK[2], cs8K[2], roffV[2], cs8V[2];
#pragma unroll
    for (int p = 0; p < 2; p++) {
        const int idx = p * 256 + tid;
        const int r = idx >> 3, cs = idx & 7;
        kwo[p] = r * 128 + ((cs * 16) ^ (((r ^ (r >> 3)) & 7) << 4));
        roffK[p] = r;
        cs8K[p] = cs * 8;
        const int B = p * 4096 + tid * 16;
        roffV[p] = ((B >> 7) & 15) * 4 + ((B >> 5) & 3);
        cs8V[p] = ((B >> 11) * 2 + ((B >> 4) & 1)) * 8;
    }
    const int vwo_base = tid * 16;  // + p*4096, linear
    const unsigned short* kvb =
        qkv + (size_t)b * T_SEQ * 3072 + INNER + h * HEAD_DIM;  // K base

    // split ranges per half
    const int lenA = (T_SEQ - qA) >> 6, cA = (lenA + 1) >> 1;
    const int lenB = (T_SEQ - qB) >> 6, cB = (lenB + 1) >> 1;
    const int begA = s ? qA + cA * KB : qA;
    const int endA = s ? T_SEQ : qA + cA * KB;
    const int begB = s ? qB + cB * KB : qB;
    const int endB = s ? T_SEQ : qB + cB * KB;

    u16x8 kreg[2], vreg[2];
#define LDTILE(ktn)                                                          \
    {                                                                        \
        _Pragma("unroll") for (int p = 0; p < 2; p++) {                      \
            kreg[p] = *(const u16x8*)(kvb + (size_t)((ktn) + roffK[p]) * 3072 \
                                      + cs8K[p]);                            \
            vreg[p] = *(const u16x8*)(kvb + (size_t)((ktn) + roffV[p]) * 3072 \
                                      + INNER + cs8V[p]);                    \
        }                                                                    \
    }

    LDTILE(begA);  // A range never empty (lenA >= 17, cA >= 9)
    int buf = 0;

    for (int half = 0; half < 2; half++) {
        const int q0 = half ? qB : qA;
        const int kbeg = half ? begB : begA;
        const int kend = half ? endB : endA;

        const unsigned short* qbase =
            qkv + (size_t)(b * T_SEQ + q0 + wid * 16 + lr) * 3072 + h * HEAD_DIM;
        const bf16x8 qf0 = *(const bf16x8*)(qbase + lg * 8);
        const bf16x8 qf1 = *(const bf16x8*)(qbase + 32 + lg * 8);

        float lsum = 0.f;
        f32x4 accO[4] = {};

        for (int kt = kbeg; kt < kend; kt += KB) {
            const int ktn = (kt + KB < kend) ? kt + KB
                          : (half == 0 && begB < endB ? begB : -1);

#pragma unroll
            for (int p = 0; p < 2; p++) {
                *(u16x8*)((char*)Kl[buf] + kwo[p]) = kreg[p];
                *(u16x8*)((char*)Vs[buf] + p * 4096 + vwo_base) = vreg[p];
            }
            if (ktn >= 0) LDTILE(ktn);
            lds_barrier();

            // ---- S^T = K Q^T ----
            f32x4 sc[4];
            __builtin_amdgcn_s_setprio(1);
#pragma unroll
            for (int f = 0; f < 4; f++) {
                const int r = f * 16 + lr;
                const int sw = ((r ^ (r >> 3)) & 7) << 4;
                bf16x8 k0 = *(const bf16x8*)((char*)Kl[buf] + r * 128 + ((lg * 16) ^ sw));
                bf16x8 k1 = *(const bf16x8*)((char*)Kl[buf] + r * 128 + ((64 + lg * 16) ^ sw));
                f32x4 z = {0.f, 0.f, 0.f, 0.f};
                z = __builtin_amdgcn_mfma_f32_16x16x32_bf16(k0, qf0, z, 0, 0, 0);
                sc[f] = __builtin_amdgcn_mfma_f32_16x16x32_bf16(k1, qf1, z, 0, 0, 0);
            }
            __builtin_amdgcn_s_setprio(0);

            if (kt == q0) {  // diag tile (only in s=0 ranges)
#pragma unroll
                for (int f = 0; f < 4; f++)
#pragma unroll
                    for (int i = 0; i < 4; i++) {
                        const int kg = f * 16 + lg * 4 + i;
                        if (kg < wid * 16 + lr) sc[f][i] = -1e30f;
                    }
            }

            // ---- issue ALL 16 V transpose reads ----
            const unsigned vsb = ldsa(Vs[buf]) + lr * 8 + lg * 128;
            u32x2 vf[4][4];
            TR1(vf[0][0], vsb, 0);    TR1(vf[0][1], vsb, 2048);
            TR1(vf[0][2], vsb, 4096); TR1(vf[0][3], vsb, 6144);
            TR1(vf[1][0], vsb, 512);  TR1(vf[1][1], vsb, 2560);
            TR1(vf[1][2], vsb, 4608); TR1(vf[1][3], vsb, 6656);
            TR1(vf[2][0], vsb, 1024); TR1(vf[2][1], vsb, 3072);
            TR1(vf[2][2], vsb, 5120); TR1(vf[2][3], vsb, 7168);
            TR1(vf[3][0], vsb, 1536); TR1(vf[3][1], vsb, 3584);
            TR1(vf[3][2], vsb, 5632); TR1(vf[3][3], vsb, 7680);

            // ---- static softmax (M=0) ----
            float rs = 0.f;
            u32x2 av[4];
#pragma unroll
            for (int f = 0; f < 4; f++) {
                float p0 = exp2f(sc[f][0]);
                float p1 = exp2f(sc[f][1]);
                float p2 = exp2f(sc[f][2]);
                float p3 = exp2f(sc[f][3]);
                rs += (p0 + p1) + (p2 + p3);
                av[f][0] = cvt_pk_bf16(p0, p1);
                av[f][1] = cvt_pk_bf16(p2, p3);
            }
            rs += __shfl_xor(rs, 16);
            rs += __shfl_xor(rs, 32);
            lsum += rs;

            asm volatile("s_waitcnt lgkmcnt(0)" ::: "memory");
            __builtin_amdgcn_sched_barrier(0);
            __builtin_amdgcn_s_setprio(1);
#pragma unroll
            for (int f = 0; f < 4; f++)
#pragma unroll
                for (int df = 0; df < 4; df++)
                    accO[df] = mfma16(av[f], vf[f][df], accO[df]);
            __builtin_amdgcn_s_setprio(0);
            buf ^= 1;
        }

        // ---- store UNNORMALIZED partial: accO bf16 + lsum fp32 ----
#pragma unroll
        for (int df = 0; df < 4; df++)
#pragma unroll
            for (int i = 0; i < 4; i++) {
                const int row = b * T_SEQ + q0 + wid * 16 + lg * 4 + i;
                prt[(size_t)row * INNER + h * HEAD_DIM + df * 16 + lr] =
                    f2bf(accO[df][i]);
            }
        if (lane < 16)
            lsp[(b * T_SEQ + q0 + wid * 16 + lane) * 16 + h] = lsum;
    }
#undef LDTILE
}

// ---------------------------------------------------------------------------
extern "C" void kernel_launch(void* const* d_in, const int* in_sizes, int n_in,
                              void* d_out, int out_size, void* d_ws, size_t ws_size,
                              hipStream_t stream) {
    const float* x     = (const float*)d_in[0];
    const float* qkv_w = (const float*)d_in[1];
    const float* qkv_b = (const float*)d_in[2];
    const float* out_w = (const float*)d_in[3];
    const float* out_b = (const float*)d_in[4];
    float* out = (float*)d_out;

    // ws layout (48 MB peak, liveness-overlapped):
    //  [0, 8M)    xb  (x bf16; dead after QKV)  -> part1 accO (attn)
    //  [8M,14M)   wqb (dead after QKV)          -> lsum0/lsum1 @ [8M,8.5M)
    //  [14M,16M)  wob (live till out-proj)
    //  [16M,40M)  qkvb (dead after attn)
    //  [40M,48M)  part0 accO
    char* ws = (char*)d_ws;
    unsigned short* xb    = (unsigned short*)(ws);
    unsigned short* part1 = (unsigned short*)(ws);
    unsigned short* wqb   = (unsigned short*)(ws + (8l << 20));
    float*          ls0   = (float*)(ws + (8l << 20));
    float*          ls1   = (float*)(ws + (8l << 20) + (256l << 10));
    unsigned short* wob   = (unsigned short*)(ws + (14l << 20));
    unsigned short* qkvb  = (unsigned short*)(ws + (16l << 20));
    unsigned short* part0 = (unsigned short*)(ws + (40l << 20));

    const float cexp = 0.18033688011112042f;  // log2(e)/sqrt(HEAD_DIM)

    cvt_f32_bf16<<<4096, 256, 0, stream>>>(x, xb, TOKENS * D_MODEL);
    cvt_f32_bf16<<<3072, 256, 0, stream>>>(qkv_w, wqb, 3 * INNER * D_MODEL);
    cvt_f32_bf16<<<1024, 256, 0, stream>>>(out_w, wob, D_MODEL * INNER);

    gemm_nt<<<dim3(3 * INNER / 128, TOKENS / 128), 256, 0, stream>>>(
        xb, wqb, qkv_b, qkvb, TOKENS, 3 * INNER, D_MODEL, INNER, cexp);

    attn_fwd<<<1024, 256, 0, stream>>>(qkvb, part0, part1, ls0, ls1);

    gemm_out<<<dim3(D_MODEL / 128, TOKENS / 64), 256, 0, stream>>>(
        part0, part1, ls0, ls1, wob, out_b, out, TOKENS, D_MODEL, INNER);
}